// Round 1
// baseline (1048.088 us; speedup 1.0000x reference)
//
#include <hip/hip_runtime.h>

// Problem constants (from reference)
constexpr int Bn   = 4096;
constexpr int D_IN = 128;
constexpr int HID  = 200;
constexpr int DIM  = 256;
constexpr int Mm_  = 32;
constexpr int TR   = 16;        // rows per block
constexpr int ZS   = DIM + 4;   // zs stride (16B aligned, bank-staggered)
constexpr int AS   = DIM + 4;   // A stride in LDS

// ---------------------------------------------------------------------------
// k_prep: KA = inv(A A^T + 1e-6 I) @ A   -> d_ws (32*256 floats)
// One block, 256 threads. G is diagonally dominant (Wishart, diag~1,
// offdiag~1/16) -> Gauss-Jordan without pivoting is stable.
// ---------------------------------------------------------------------------
__global__ __launch_bounds__(256) void k_prep(const float* __restrict__ A,
                                              float* __restrict__ KA) {
  __shared__ float As[Mm_ * DIM];        // 32x256
  __shared__ float Gm[Mm_ * 65];         // [32][64+1] augmented [G | I]
  __shared__ float ck[Mm_];
  const int t = threadIdx.x;

  for (int idx = t; idx < Mm_ * DIM; idx += 256) As[idx] = A[idx];
  __syncthreads();

  for (int idx = t; idx < Mm_ * Mm_; idx += 256) {
    int i = idx >> 5, j = idx & 31;
    float s = 0.f;
    for (int k = 0; k < DIM; ++k) s = fmaf(As[i * DIM + k], As[j * DIM + k], s);
    if (i == j) s += 1e-6f;
    Gm[i * 65 + j] = s;
    Gm[i * 65 + 32 + j] = (i == j) ? 1.f : 0.f;
  }
  __syncthreads();

  for (int k = 0; k < Mm_; ++k) {
    if (t < Mm_) ck[t] = Gm[t * 65 + k];
    __syncthreads();
    float ip = 1.f / ck[k];
    if (t < 64) Gm[k * 65 + t] *= ip;
    __syncthreads();
    for (int idx = t; idx < Mm_ * 64; idx += 256) {
      int i = idx >> 6, j = idx & 63;
      if (i != k) Gm[i * 65 + j] = fmaf(-ck[i], Gm[k * 65 + j], Gm[i * 65 + j]);
    }
    __syncthreads();
  }

  // KA = Ginv @ A
  for (int idx = t; idx < Mm_ * DIM; idx += 256) {
    int m = idx >> 8, j = idx & 255;
    float s = 0.f;
    for (int n = 0; n < Mm_; ++n) s = fmaf(Gm[m * 65 + 32 + n], As[n * DIM + j], s);
    KA[idx] = s;
  }
}

// ---------------------------------------------------------------------------
// k_main: fused MLP + 100 DR iterations + final affine projection.
// Grid: Bn/TR = 256 blocks, 256 threads.
// ---------------------------------------------------------------------------
__global__ __launch_bounds__(256) void k_main(
    const float* __restrict__ x,  const float* __restrict__ bmat,
    const float* __restrict__ W1, const float* __restrict__ b1,
    const float* __restrict__ W2, const float* __restrict__ b2,
    const float* __restrict__ W3, const float* __restrict__ b3,
    const float* __restrict__ A,  const float* __restrict__ KA,
    const int* __restrict__ n_iter_p, float* __restrict__ out) {

  // ubuf: MLP scratch (xs/h1/h2) first, then re-used to hold A (32 x AS).
  __shared__ float ubuf[8768];                 // max(2112+3328+3328, 32*260)
  __shared__ float zs[TR * ZS];                // z tile, column-accessible
  __shared__ float rs[TR * Mm_];               // residual r per row
  __shared__ float bsh[TR * Mm_];              // b tile

  const int t = threadIdx.x;
  const int row0 = blockIdx.x * TR;

  // ---- stage x tile ----
  float* xs = ubuf;                  // [TR][132]
  float* h1 = ubuf + TR * 132;       // [TR][208]
  float* h2 = h1 + TR * 208;         // [TR][208]
  for (int idx = t; idx < TR * D_IN; idx += 256) {
    int r = idx >> 7, k = idx & 127;
    xs[r * 132 + k] = x[(size_t)(row0 + r) * D_IN + k];
  }
  __syncthreads();

  // ---- MLP ----
  {
    const int rg = t >> 6;   // wave id -> rows rg*4 .. rg*4+3
    const int oc = t & 63;
    // h1 = relu(x @ W1 + b1)
    for (int o = oc; o < HID; o += 64) {
      float a0 = b1[o], a1 = a0, a2 = a0, a3 = a0;
      for (int k = 0; k < D_IN; ++k) {
        float w = W1[k * HID + o];
        a0 = fmaf(xs[(rg * 4 + 0) * 132 + k], w, a0);
        a1 = fmaf(xs[(rg * 4 + 1) * 132 + k], w, a1);
        a2 = fmaf(xs[(rg * 4 + 2) * 132 + k], w, a2);
        a3 = fmaf(xs[(rg * 4 + 3) * 132 + k], w, a3);
      }
      h1[(rg * 4 + 0) * 208 + o] = fmaxf(a0, 0.f);
      h1[(rg * 4 + 1) * 208 + o] = fmaxf(a1, 0.f);
      h1[(rg * 4 + 2) * 208 + o] = fmaxf(a2, 0.f);
      h1[(rg * 4 + 3) * 208 + o] = fmaxf(a3, 0.f);
    }
    __syncthreads();
    // h2 = relu(h1 @ W2 + b2)
    for (int o = oc; o < HID; o += 64) {
      float a0 = b2[o], a1 = a0, a2 = a0, a3 = a0;
      for (int k = 0; k < HID; ++k) {
        float w = W2[k * HID + o];
        a0 = fmaf(h1[(rg * 4 + 0) * 208 + k], w, a0);
        a1 = fmaf(h1[(rg * 4 + 1) * 208 + k], w, a1);
        a2 = fmaf(h1[(rg * 4 + 2) * 208 + k], w, a2);
        a3 = fmaf(h1[(rg * 4 + 3) * 208 + k], w, a3);
      }
      h2[(rg * 4 + 0) * 208 + o] = fmaxf(a0, 0.f);
      h2[(rg * 4 + 1) * 208 + o] = fmaxf(a1, 0.f);
      h2[(rg * 4 + 2) * 208 + o] = fmaxf(a2, 0.f);
      h2[(rg * 4 + 3) * 208 + o] = fmaxf(a3, 0.f);
    }
    __syncthreads();
    // y = h2 @ W3 + b3 -> zs
    for (int o = oc; o < DIM; o += 64) {
      float a0 = b3[o], a1 = a0, a2 = a0, a3 = a0;
      for (int k = 0; k < HID; ++k) {
        float w = W3[k * DIM + o];
        a0 = fmaf(h2[(rg * 4 + 0) * 208 + k], w, a0);
        a1 = fmaf(h2[(rg * 4 + 1) * 208 + k], w, a1);
        a2 = fmaf(h2[(rg * 4 + 2) * 208 + k], w, a2);
        a3 = fmaf(h2[(rg * 4 + 3) * 208 + k], w, a3);
      }
      zs[(rg * 4 + 0) * ZS + o] = a0;
      zs[(rg * 4 + 1) * ZS + o] = a1;
      zs[(rg * 4 + 2) * ZS + o] = a2;
      zs[(rg * 4 + 3) * ZS + o] = a3;
    }
  }
  __syncthreads();   // MLP done; zs holds y; ubuf now dead

  // ---- load iteration-invariant state ----
  float* Ald = ubuf;                            // [32][AS]
  for (int idx = t; idx < Mm_ * DIM; idx += 256)
    Ald[(idx >> 8) * AS + (idx & 255)] = A[idx];
  for (int idx = t; idx < TR * Mm_; idx += 256)
    bsh[idx] = bmat[(size_t)row0 * Mm_ + idx];

  float kac[Mm_];                               // KA column t (registers)
  #pragma unroll
  for (int m = 0; m < Mm_; ++m) kac[m] = KA[m * DIM + t];

  float zr[TR];                                 // z column t (registers)
  #pragma unroll
  for (int r = 0; r < TR; ++r) zr[r] = zs[r * ZS + t];
  __syncthreads();

  const int prow = t >> 4;   // phase-A row (0..15)
  const int jc   = t & 15;   // phase-A column chunk
  const int niter = n_iter_p[0];

  for (int it = 0; it <= niter; ++it) {
    // ======== Phase A: r[prow][m] = sum_j A[m][j] z[prow][j] - b ========
    float p[Mm_];
    #pragma unroll
    for (int m = 0; m < Mm_; ++m) p[m] = 0.f;
    #pragma unroll
    for (int s = 0; s < 4; ++s) {
      const float4 z4 = *(const float4*)(zs + prow * ZS + jc * 4 + 64 * s);
      #pragma unroll
      for (int m = 0; m < Mm_; ++m) {
        const float4 a4 = *(const float4*)(Ald + m * AS + jc * 4 + 64 * s);
        p[m] = fmaf(z4.x, a4.x, p[m]);
        p[m] = fmaf(z4.y, a4.y, p[m]);
        p[m] = fmaf(z4.z, a4.z, p[m]);
        p[m] = fmaf(z4.w, a4.w, p[m]);
      }
    }
    // butterfly over the 16 jc lanes (stays within the wave; rows = lane>>4)
    #pragma unroll
    for (int m = 0; m < Mm_; ++m) p[m] += __shfl_xor(p[m], 1, 64);
    #pragma unroll
    for (int m = 0; m < Mm_; ++m) p[m] += __shfl_xor(p[m], 2, 64);
    #pragma unroll
    for (int m = 0; m < Mm_; ++m) p[m] += __shfl_xor(p[m], 4, 64);
    #pragma unroll
    for (int m = 0; m < Mm_; ++m) p[m] += __shfl_xor(p[m], 8, 64);
    if (jc == 0) {
      #pragma unroll
      for (int m = 0; m < Mm_; ++m)
        rs[prow * Mm_ + m] = p[m] - bsh[prow * Mm_ + m];
    }
    __syncthreads();

    // ======== Phase B: per-column update (KA column + z column in regs) ====
    if (it < niter) {
      #pragma unroll
      for (int r = 0; r < TR; ++r) {
        float acc = 0.f;
        #pragma unroll
        for (int m = 0; m < Mm_; m += 4) {
          const float4 r4 = *(const float4*)(rs + r * Mm_ + m);
          acc = fmaf(r4.x, kac[m + 0], acc);
          acc = fmaf(r4.y, kac[m + 1], acc);
          acc = fmaf(r4.z, kac[m + 2], acc);
          acc = fmaf(r4.w, kac[m + 3], acc);
        }
        float z = zr[r];
        float u = z - acc;                       // p_aff(z)
        float v = 2.f * u - z;                   // reflect
        v = fminf(fmaxf(v, 0.f), 1.f);           // box projection
        z = fmaf(1.7f, v - u, z);                // z += sigma*omega*(v-u)
        zr[r] = z;
        zs[r * ZS + t] = z;
      }
      __syncthreads();
    } else {
      // final: out = p_aff(z_final)
      #pragma unroll
      for (int r = 0; r < TR; ++r) {
        float acc = 0.f;
        #pragma unroll
        for (int m = 0; m < Mm_; m += 4) {
          const float4 r4 = *(const float4*)(rs + r * Mm_ + m);
          acc = fmaf(r4.x, kac[m + 0], acc);
          acc = fmaf(r4.y, kac[m + 1], acc);
          acc = fmaf(r4.z, kac[m + 2], acc);
          acc = fmaf(r4.w, kac[m + 3], acc);
        }
        out[(size_t)(row0 + r) * DIM + t] = zr[r] - acc;
      }
    }
  }
}

// ---------------------------------------------------------------------------
extern "C" void kernel_launch(void* const* d_in, const int* in_sizes, int n_in,
                              void* d_out, int out_size, void* d_ws, size_t ws_size,
                              hipStream_t stream) {
  const float* x    = (const float*)d_in[0];
  const float* bmat = (const float*)d_in[1];
  const float* W1   = (const float*)d_in[2];
  const float* b1   = (const float*)d_in[3];
  const float* W2   = (const float*)d_in[4];
  const float* b2   = (const float*)d_in[5];
  const float* W3   = (const float*)d_in[6];
  const float* b3   = (const float*)d_in[7];
  const float* A    = (const float*)d_in[8];
  const int*  n_it  = (const int*)d_in[10];
  float* KA  = (float*)d_ws;          // 32*256 floats = 32 KB
  float* out = (float*)d_out;

  hipLaunchKernelGGL(k_prep, dim3(1), dim3(256), 0, stream, A, KA);
  hipLaunchKernelGGL(k_main, dim3(Bn / TR), dim3(256), 0, stream,
                     x, bmat, W1, b1, W2, b2, W3, b3, A, KA, n_it, out);
}

// Round 3
// 360.512 us; speedup vs baseline: 2.9072x; 2.9072x over previous
//
#include <hip/hip_runtime.h>
#include <hip/hip_bf16.h>

typedef float f4v  __attribute__((ext_vector_type(4)));
typedef short short8 __attribute__((ext_vector_type(8)));

constexpr int Bn   = 4096;
constexpr int D_IN = 128;
constexpr int HID  = 200;
constexpr int DIM  = 256;
constexpr int Mm_  = 32;
constexpr int TR   = 16;         // rows per block
constexpr int ZS   = 260;        // zs row stride (dwords, 16B aligned, bank-friendly)
constexpr int RS_  = 36;         // rbuf row stride (dwords)
constexpr int RBH  = 16 * RS_;   // per-K-half rbuf size = 576

// ---------------------------------------------------------------------------
// k_prep: KA = inv(A A^T + 1e-6 I) @ A   -> d_ws (32*256 floats)
// One block, 256 threads. G is diagonally dominant -> Gauss-Jordan w/o pivot.
// ---------------------------------------------------------------------------
__global__ __launch_bounds__(256) void k_prep(const float* __restrict__ A,
                                              float* __restrict__ KA) {
  __shared__ float As[Mm_ * DIM];
  __shared__ float Gm[Mm_ * 65];
  __shared__ float ck[Mm_];
  const int t = threadIdx.x;

  for (int idx = t; idx < Mm_ * DIM; idx += 256) As[idx] = A[idx];
  __syncthreads();

  for (int idx = t; idx < Mm_ * Mm_; idx += 256) {
    int i = idx >> 5, j = idx & 31;
    float s = 0.f;
    for (int k = 0; k < DIM; ++k) s = fmaf(As[i * DIM + k], As[j * DIM + k], s);
    if (i == j) s += 1e-6f;
    Gm[i * 65 + j] = s;
    Gm[i * 65 + 32 + j] = (i == j) ? 1.f : 0.f;
  }
  __syncthreads();

  for (int k = 0; k < Mm_; ++k) {
    if (t < Mm_) ck[t] = Gm[t * 65 + k];
    __syncthreads();
    float ip = 1.f / ck[k];
    if (t < 64) Gm[k * 65 + t] *= ip;
    __syncthreads();
    for (int idx = t; idx < Mm_ * 64; idx += 256) {
      int i = idx >> 6, j = idx & 63;
      if (i != k) Gm[i * 65 + j] = fmaf(-ck[i], Gm[k * 65 + j], Gm[i * 65 + j]);
    }
    __syncthreads();
  }

  for (int idx = t; idx < Mm_ * DIM; idx += 256) {
    int m = idx >> 8, j = idx & 255;
    float s = 0.f;
    for (int n = 0; n < Mm_; ++n) s = fmaf(Gm[m * 65 + 32 + n], As[n * DIM + j], s);
    KA[idx] = s;
  }
}

// ---- split-bf16 helpers ----------------------------------------------------
__device__ inline unsigned cvt2(float x, float y) {
  union { __hip_bfloat162 h; unsigned u; } c;
  c.h = __float22bfloat162_rn(float2{x, y});
  return c.u;   // low 16 = bf16(x), high 16 = bf16(y)
}
__device__ inline void split_pair(float x, float y, unsigned& hpk, unsigned& lpk) {
  hpk = cvt2(x, y);
  float hx = __uint_as_float(hpk << 16);
  float hy = __uint_as_float(hpk & 0xffff0000u);
  lpk = cvt2(x - hx, y - hy);
}
union S8U { unsigned u[4]; short8 s; };
__device__ inline void split8(const float v[8], short8& hi, short8& lo) {
  S8U h, l;
  #pragma unroll
  for (int d = 0; d < 4; ++d) split_pair(v[2*d], v[2*d+1], h.u[d], l.u[d]);
  hi = h.s; lo = l.s;
}

__device__ inline f4v mfma16(short8 a, short8 b, f4v c) {
  return __builtin_amdgcn_mfma_f32_16x16x32_bf16(a, b, c, 0, 0, 0);
}

// ---------------------------------------------------------------------------
// k_main: fused MLP + 100 DR iterations (MFMA split-bf16) + final projection.
// Grid: 256 blocks x 256 threads (4 waves). TR=16 rows per block.
// Wave w: phase A computes m-tile (w&1), K-half (w>>1); phase B computes
// output col-tiles 4w..4w+3.
// ---------------------------------------------------------------------------
__global__ __launch_bounds__(256, 1) void k_main(
    const float* __restrict__ x,  const float* __restrict__ bmat,
    const float* __restrict__ W1, const float* __restrict__ b1,
    const float* __restrict__ W2, const float* __restrict__ b2,
    const float* __restrict__ W3, const float* __restrict__ b3,
    const float* __restrict__ A,  const float* __restrict__ KA,
    const int* __restrict__ n_iter_p, float* __restrict__ out) {

  __shared__ float ubuf[8768];                       // MLP scratch
  __shared__ __align__(16) float zs[TR * ZS];        // z tile fp32
  __shared__ __align__(16) float rbuf[2 * RBH];      // phase-A partials (2 K-halves)

  const int t = threadIdx.x;
  const int row0 = blockIdx.x * TR;

  // ---- stage x tile ----
  float* xs = ubuf;                  // [TR][132]
  float* h1 = ubuf + TR * 132;       // [TR][208]
  float* h2 = h1 + TR * 208;         // [TR][208]
  for (int idx = t; idx < TR * D_IN; idx += 256) {
    int r = idx >> 7, k = idx & 127;
    xs[r * 132 + k] = x[(size_t)(row0 + r) * D_IN + k];
  }
  __syncthreads();

  // ---- MLP (VALU) ----
  {
    const int rg = t >> 6;
    const int oc = t & 63;
    for (int o = oc; o < HID; o += 64) {
      float a0 = b1[o], a1 = a0, a2 = a0, a3 = a0;
      for (int k = 0; k < D_IN; ++k) {
        float w = W1[k * HID + o];
        a0 = fmaf(xs[(rg * 4 + 0) * 132 + k], w, a0);
        a1 = fmaf(xs[(rg * 4 + 1) * 132 + k], w, a1);
        a2 = fmaf(xs[(rg * 4 + 2) * 132 + k], w, a2);
        a3 = fmaf(xs[(rg * 4 + 3) * 132 + k], w, a3);
      }
      h1[(rg * 4 + 0) * 208 + o] = fmaxf(a0, 0.f);
      h1[(rg * 4 + 1) * 208 + o] = fmaxf(a1, 0.f);
      h1[(rg * 4 + 2) * 208 + o] = fmaxf(a2, 0.f);
      h1[(rg * 4 + 3) * 208 + o] = fmaxf(a3, 0.f);
    }
    __syncthreads();
    for (int o = oc; o < HID; o += 64) {
      float a0 = b2[o], a1 = a0, a2 = a0, a3 = a0;
      for (int k = 0; k < HID; ++k) {
        float w = W2[k * HID + o];
        a0 = fmaf(h1[(rg * 4 + 0) * 208 + k], w, a0);
        a1 = fmaf(h1[(rg * 4 + 1) * 208 + k], w, a1);
        a2 = fmaf(h1[(rg * 4 + 2) * 208 + k], w, a2);
        a3 = fmaf(h1[(rg * 4 + 3) * 208 + k], w, a3);
      }
      h2[(rg * 4 + 0) * 208 + o] = fmaxf(a0, 0.f);
      h2[(rg * 4 + 1) * 208 + o] = fmaxf(a1, 0.f);
      h2[(rg * 4 + 2) * 208 + o] = fmaxf(a2, 0.f);
      h2[(rg * 4 + 3) * 208 + o] = fmaxf(a3, 0.f);
    }
    __syncthreads();
    for (int o = oc; o < DIM; o += 64) {
      float a0 = b3[o], a1 = a0, a2 = a0, a3 = a0;
      for (int k = 0; k < HID; ++k) {
        float w = W3[k * DIM + o];
        a0 = fmaf(h2[(rg * 4 + 0) * 208 + k], w, a0);
        a1 = fmaf(h2[(rg * 4 + 1) * 208 + k], w, a1);
        a2 = fmaf(h2[(rg * 4 + 2) * 208 + k], w, a2);
        a3 = fmaf(h2[(rg * 4 + 3) * 208 + k], w, a3);
      }
      zs[(rg * 4 + 0) * ZS + o] = a0;
      zs[(rg * 4 + 1) * ZS + o] = a1;
      zs[(rg * 4 + 2) * ZS + o] = a2;
      zs[(rg * 4 + 3) * ZS + o] = a3;
    }
  }
  __syncthreads();

  // ---- invariant MFMA operand fragments (registers) ----
  const int lane = t & 63;
  const int w    = t >> 6;       // wave id 0..3
  const int quad = lane >> 4;
  const int l15  = lane & 15;
  const int T    = w & 1;        // phase-A m-tile (m 0-15 / 16-31)
  const int kh   = w >> 1;       // phase-A K-half

  short8 abh[4], abl[4];         // phase-A B-operand (A^T), 4 k-steps
  #pragma unroll
  for (int s = 0; s < 4; ++s) {
    int kb = 128 * kh + 32 * s + 8 * quad;
    const float* ap = A + (l15 + 16 * T) * DIM + kb;   // B[k][n] = A[n][k]
    float v[8];
    #pragma unroll
    for (int j = 0; j < 8; ++j) v[j] = ap[j];
    split8(v, abh[s], abl[s]);
  }

  f4v binit = {0.f, 0.f, 0.f, 0.f};
  if (kh == 0) {
    #pragma unroll
    for (int r = 0; r < 4; ++r)
      binit[r] = -bmat[(size_t)(row0 + 4 * quad + r) * Mm_ + l15 + 16 * T];
  }

  short8 kbh[4], kbl[4];         // phase-B B-operand (KA), 4 col-tiles per wave
  #pragma unroll
  for (int u = 0; u < 4; ++u) {
    int col = l15 + 16 * (4 * w + u);
    float v[8];
    #pragma unroll
    for (int j = 0; j < 8; ++j) v[j] = KA[(8 * quad + j) * DIM + col]; // B[k=m][n=col]
    split8(v, kbh[u], kbl[u]);
  }

  const int niter = n_iter_p[0];

  for (int it = 0; it <= niter; ++it) {
    // ======== Phase A: partial r = z @ A^T (this wave: m-tile T, K-half kh) ====
    f4v a0 = binit, a1 = {0.f, 0.f, 0.f, 0.f};
    const float* zrow = zs + l15 * ZS + 128 * kh + 8 * quad;
    #pragma unroll
    for (int s = 0; s < 4; ++s) {
      const float* zp = zrow + 32 * s;
      f4v za = *(const f4v*)zp;
      f4v zb = *(const f4v*)(zp + 4);
      float v[8] = {za[0], za[1], za[2], za[3], zb[0], zb[1], zb[2], zb[3]};
      short8 zh, zl;
      split8(v, zh, zl);
      if (s & 1) {
        a1 = mfma16(zh, abh[s], a1);
        a1 = mfma16(zl, abh[s], a1);
        a1 = mfma16(zh, abl[s], a1);
      } else {
        a0 = mfma16(zh, abh[s], a0);
        a0 = mfma16(zl, abh[s], a0);
        a0 = mfma16(zh, abl[s], a0);
      }
    }
    f4v rA = a0 + a1;
    // store partial C: rbuf[kh][row=4*quad+r][m=l15+16T]
    #pragma unroll
    for (int r = 0; r < 4; ++r)
      rbuf[kh * RBH + (4 * quad + r) * RS_ + l15 + 16 * T] = rA[r];
    __syncthreads();

    // ======== Phase B: w = r @ KA (this wave: col-tiles 4w..4w+3) ========
    // gather r in A-operand layout: i = l15, m = 8*quad + j; sum the 2 K-halves
    const float* rp = rbuf + l15 * RS_ + 8 * quad;
    f4v p0  = *(const f4v*)rp;
    f4v p0b = *(const f4v*)(rp + 4);
    f4v p1  = *(const f4v*)(rp + RBH);
    f4v p1b = *(const f4v*)(rp + RBH + 4);
    float rv[8] = {p0[0] + p1[0], p0[1] + p1[1], p0[2] + p1[2], p0[3] + p1[3],
                   p0b[0] + p1b[0], p0b[1] + p1b[1], p0b[2] + p1b[2], p0b[3] + p1b[3]};
    short8 rh, rl;
    split8(rv, rh, rl);

    f4v accB[4];
    #pragma unroll
    for (int u = 0; u < 4; ++u) {
      f4v c = {0.f, 0.f, 0.f, 0.f};
      c = mfma16(rh, kbh[u], c);
      c = mfma16(rl, kbh[u], c);
      c = mfma16(rh, kbl[u], c);
      accB[u] = c;
    }

    // ======== update / final ========
    if (it < niter) {
      #pragma unroll
      for (int u = 0; u < 4; ++u) {
        int col = l15 + 16 * (4 * w + u);
        #pragma unroll
        for (int r = 0; r < 4; ++r) {
          int row = 4 * quad + r;
          float z = zs[row * ZS + col];
          float wv = accB[u][r];
          float vv = fminf(fmaxf(z - 2.f * wv, 0.f), 1.f);  // clip(2u - z)
          zs[row * ZS + col] = fmaf(1.7f, vv - z + wv, z);  // z += 1.7*(v-u)
        }
      }
      __syncthreads();
    } else {
      #pragma unroll
      for (int u = 0; u < 4; ++u) {
        int col = l15 + 16 * (4 * w + u);
        #pragma unroll
        for (int r = 0; r < 4; ++r) {
          int row = 4 * quad + r;
          out[(size_t)(row0 + row) * DIM + col] = zs[row * ZS + col] - accB[u][r];
        }
      }
    }
  }
}

// ---------------------------------------------------------------------------
extern "C" void kernel_launch(void* const* d_in, const int* in_sizes, int n_in,
                              void* d_out, int out_size, void* d_ws, size_t ws_size,
                              hipStream_t stream) {
  const float* x    = (const float*)d_in[0];
  const float* bmat = (const float*)d_in[1];
  const float* W1   = (const float*)d_in[2];
  const float* b1   = (const float*)d_in[3];
  const float* W2   = (const float*)d_in[4];
  const float* b2   = (const float*)d_in[5];
  const float* W3   = (const float*)d_in[6];
  const float* b3   = (const float*)d_in[7];
  const float* A    = (const float*)d_in[8];
  const int*  n_it  = (const int*)d_in[10];
  float* KA  = (float*)d_ws;
  float* out = (float*)d_out;

  hipLaunchKernelGGL(k_prep, dim3(1), dim3(256), 0, stream, A, KA);
  hipLaunchKernelGGL(k_main, dim3(Bn / TR), dim3(256), 0, stream,
                     x, bmat, W1, b1, W2, b2, W3, b3, A, KA, n_it, out);
}

// Round 4
// 294.088 us; speedup vs baseline: 3.5639x; 1.2259x over previous
//
#include <hip/hip_runtime.h>
#include <hip/hip_bf16.h>

typedef float    f4v    __attribute__((ext_vector_type(4)));
typedef short    short8 __attribute__((ext_vector_type(8)));
typedef unsigned u2v    __attribute__((ext_vector_type(2)));

constexpr int Bn = 4096, D_IN = 128, HID = 200, DIM = 256, TR = 16;

// ---------------------------------------------------------------------------
// k_prep: KAT[n][m] = (inv(A A^T + 1e-6 I) @ A)^T   -> d_ws (256*32 floats)
// ---------------------------------------------------------------------------
__global__ __launch_bounds__(256) void k_prep(const float* __restrict__ A,
                                              float* __restrict__ KAT) {
  __shared__ float As[32 * 256];
  __shared__ float Gm[32 * 68];   // [32][64] augmented [G|I], stride 68 (16B-aligned cols)
  __shared__ float ck[32];
  const int t = threadIdx.x;

  for (int i = t; i < 2048; i += 256) ((f4v*)As)[i] = ((const f4v*)A)[i];

  // G = A A^T + eps I  (global f4 reads; A is L2-hot)
  for (int p = 0; p < 4; ++p) {
    int idx = t + 256 * p, i = idx >> 5, j = idx & 31;
    f4v acc = {0.f, 0.f, 0.f, 0.f};
    const f4v* ai = (const f4v*)(A + i * 256);
    const f4v* aj = (const f4v*)(A + j * 256);
    for (int k = 0; k < 64; ++k) acc += ai[k] * aj[k];
    float s = acc[0] + acc[1] + acc[2] + acc[3];
    if (i == j) s += 1e-6f;
    Gm[i * 68 + j] = s;
    Gm[i * 68 + 32 + j] = (i == j) ? 1.f : 0.f;
  }
  __syncthreads();

  // Gauss-Jordan (diagonally dominant; no pivoting)
  for (int k = 0; k < 32; ++k) {
    if (t < 32) ck[t] = Gm[t * 68 + k];
    __syncthreads();
    float ip = 1.f / ck[k];
    if (t < 64) Gm[k * 68 + t] *= ip;
    __syncthreads();
    for (int idx = t; idx < 2048; idx += 256) {
      int i = idx >> 6, j = idx & 63;
      if (i != k) Gm[i * 68 + j] = fmaf(-ck[i], Gm[k * 68 + j], Gm[i * 68 + j]);
    }
    __syncthreads();
  }

  // KAT[j][m] = sum_n Ginv[m][n] * As[n][j]   (thread j = t, column cached in regs)
  float colA[32];
  #pragma unroll
  for (int n = 0; n < 32; ++n) colA[n] = As[n * 256 + t];
  float res[32];
  #pragma unroll
  for (int m = 0; m < 32; ++m) {
    float s = 0.f;
    const f4v* g4 = (const f4v*)&Gm[m * 68 + 32];
    #pragma unroll
    for (int n4 = 0; n4 < 8; ++n4) {
      f4v g = g4[n4];
      s = fmaf(g[0], colA[4 * n4 + 0], s);
      s = fmaf(g[1], colA[4 * n4 + 1], s);
      s = fmaf(g[2], colA[4 * n4 + 2], s);
      s = fmaf(g[3], colA[4 * n4 + 3], s);
    }
    res[m] = s;
  }
  #pragma unroll
  for (int m4 = 0; m4 < 8; ++m4) {
    f4v v = {res[4 * m4], res[4 * m4 + 1], res[4 * m4 + 2], res[4 * m4 + 3]};
    *(f4v*)&KAT[t * 32 + 4 * m4] = v;
  }
}

// ---- split-bf16 helpers ----------------------------------------------------
__device__ inline unsigned cvt2(float x, float y) {
  union { __hip_bfloat162 h; unsigned u; } c;
  c.h = __float22bfloat162_rn(float2{x, y});
  return c.u;   // low16 = bf16(x), high16 = bf16(y)
}
__device__ inline void split_pair(float x, float y, unsigned& hp, unsigned& lp) {
  hp = cvt2(x, y);
  float hx = __uint_as_float(hp << 16);
  float hy = __uint_as_float(hp & 0xffff0000u);
  lp = cvt2(x - hx, y - hy);
}
union S8U { unsigned u[4]; short8 s; };
__device__ inline void split8(const float v[8], short8& hi, short8& lo) {
  S8U h, l;
  #pragma unroll
  for (int d = 0; d < 4; ++d) split_pair(v[2 * d], v[2 * d + 1], h.u[d], l.u[d]);
  hi = h.s; lo = l.s;
}
__device__ inline f4v mfma16(short8 a, short8 b, f4v c) {
  return __builtin_amdgcn_mfma_f32_16x16x32_bf16(a, b, c, 0, 0, 0);
}

// ---------------------------------------------------------------------------
// k_main: fused MLP + DR iterations. z^T lives in registers (phase-B C-layout);
// z / r exchanged via fragment-ordered bf16 hi/lo LDS buffers (conflict-free).
// Phase A (waves 0,1): r^T = A z^T - b^T  (wave = K-half, both m-tiles)
// Phase B (all waves): w^T = KA^T r^T     (wave = 4 n-tiles), update in regs.
// ---------------------------------------------------------------------------
__global__ __launch_bounds__(256, 1) void k_main(
    const float* __restrict__ x,  const float* __restrict__ bmat,
    const float* __restrict__ W1, const float* __restrict__ b1,
    const float* __restrict__ W2, const float* __restrict__ b2,
    const float* __restrict__ W3, const float* __restrict__ b3,
    const float* __restrict__ A,  const float* __restrict__ KAT,
    const int* __restrict__ n_iter_p, float* __restrict__ out) {

  __shared__ float ubuf[8768];                     // MLP scratch; later y[16][260]
  __shared__ __align__(16) unsigned zfrag[4096];   // [kh][s][hi/lo][lane] 16B frags
  __shared__ __align__(16) unsigned rfrag[1024];   // [kh][hi/lo][lane] 16B frags

  const int t = threadIdx.x;
  const int lane = t & 63, wv = t >> 6, quad = lane >> 4, l15 = lane & 15;
  const int row0 = blockIdx.x * TR;

  float* xs = ubuf;            // [16][132]
  float* h1 = ubuf + 2112;     // [16][208]
  float* h2 = ubuf + 5440;     // [16][208]
  float* ys = ubuf;            // [16][260] (xs+h1 dead by then)

  for (int i = t; i < 512; i += 256) {
    int r = i >> 5, c4 = i & 31;
    *(f4v*)&xs[r * 132 + 4 * c4] = *(const f4v*)&x[(size_t)(row0 + r) * 128 + 4 * c4];
  }
  __syncthreads();

  // ---- MLP (register-blocked VALU; k via f4 LDS broadcasts) ----
  {
    const int rg = wv, oc = lane;
    const bool g3 = (oc < 8);    // HID=200: oi=3 col = oc+192 valid iff oc<8
    float acc[4][4];

    // L1: 128 -> 200, relu
    #pragma unroll
    for (int oi = 0; oi < 4; ++oi)
      #pragma unroll
      for (int r = 0; r < 4; ++r) acc[oi][r] = 0.f;
    for (int k4 = 0; k4 < 32; ++k4) {
      float xv[4][4];
      #pragma unroll
      for (int r = 0; r < 4; ++r) {
        f4v v = *(const f4v*)&xs[(4 * rg + r) * 132 + 4 * k4];
        xv[r][0] = v[0]; xv[r][1] = v[1]; xv[r][2] = v[2]; xv[r][3] = v[3];
      }
      #pragma unroll
      for (int kk = 0; kk < 4; ++kk) {
        const float* wr = W1 + (4 * k4 + kk) * 200 + oc;
        float w0 = wr[0], w1c = wr[64], w2c = wr[128];
        float w3c = g3 ? wr[192] : 0.f;
        #pragma unroll
        for (int r = 0; r < 4; ++r) {
          acc[0][r] = fmaf(xv[r][kk], w0, acc[0][r]);
          acc[1][r] = fmaf(xv[r][kk], w1c, acc[1][r]);
          acc[2][r] = fmaf(xv[r][kk], w2c, acc[2][r]);
          acc[3][r] = fmaf(xv[r][kk], w3c, acc[3][r]);
        }
      }
    }
    #pragma unroll
    for (int oi = 0; oi < 4; ++oi) {
      if (oi == 3 && !g3) continue;
      float bb = b1[oc + 64 * oi];
      #pragma unroll
      for (int r = 0; r < 4; ++r)
        h1[(4 * rg + r) * 208 + oc + 64 * oi] = fmaxf(acc[oi][r] + bb, 0.f);
    }
    __syncthreads();

    // L2: 200 -> 200, relu
    #pragma unroll
    for (int oi = 0; oi < 4; ++oi)
      #pragma unroll
      for (int r = 0; r < 4; ++r) acc[oi][r] = 0.f;
    for (int k4 = 0; k4 < 50; ++k4) {
      float xv[4][4];
      #pragma unroll
      for (int r = 0; r < 4; ++r) {
        f4v v = *(const f4v*)&h1[(4 * rg + r) * 208 + 4 * k4];
        xv[r][0] = v[0]; xv[r][1] = v[1]; xv[r][2] = v[2]; xv[r][3] = v[3];
      }
      #pragma unroll
      for (int kk = 0; kk < 4; ++kk) {
        const float* wr = W2 + (4 * k4 + kk) * 200 + oc;
        float w0 = wr[0], w1c = wr[64], w2c = wr[128];
        float w3c = g3 ? wr[192] : 0.f;
        #pragma unroll
        for (int r = 0; r < 4; ++r) {
          acc[0][r] = fmaf(xv[r][kk], w0, acc[0][r]);
          acc[1][r] = fmaf(xv[r][kk], w1c, acc[1][r]);
          acc[2][r] = fmaf(xv[r][kk], w2c, acc[2][r]);
          acc[3][r] = fmaf(xv[r][kk], w3c, acc[3][r]);
        }
      }
    }
    #pragma unroll
    for (int oi = 0; oi < 4; ++oi) {
      if (oi == 3 && !g3) continue;
      float bb = b2[oc + 64 * oi];
      #pragma unroll
      for (int r = 0; r < 4; ++r)
        h2[(4 * rg + r) * 208 + oc + 64 * oi] = fmaxf(acc[oi][r] + bb, 0.f);
    }
    __syncthreads();

    // L3: 200 -> 256 (no relu) -> ys
    #pragma unroll
    for (int oi = 0; oi < 4; ++oi)
      #pragma unroll
      for (int r = 0; r < 4; ++r) acc[oi][r] = 0.f;
    for (int k4 = 0; k4 < 50; ++k4) {
      float xv[4][4];
      #pragma unroll
      for (int r = 0; r < 4; ++r) {
        f4v v = *(const f4v*)&h2[(4 * rg + r) * 208 + 4 * k4];
        xv[r][0] = v[0]; xv[r][1] = v[1]; xv[r][2] = v[2]; xv[r][3] = v[3];
      }
      #pragma unroll
      for (int kk = 0; kk < 4; ++kk) {
        const float* wr = W3 + (4 * k4 + kk) * 256 + oc;
        float w0 = wr[0], w1c = wr[64], w2c = wr[128], w3c = wr[192];
        #pragma unroll
        for (int r = 0; r < 4; ++r) {
          acc[0][r] = fmaf(xv[r][kk], w0, acc[0][r]);
          acc[1][r] = fmaf(xv[r][kk], w1c, acc[1][r]);
          acc[2][r] = fmaf(xv[r][kk], w2c, acc[2][r]);
          acc[3][r] = fmaf(xv[r][kk], w3c, acc[3][r]);
        }
      }
    }
    __syncthreads();   // everyone done reading h2 before ys overlays ubuf
    #pragma unroll
    for (int oi = 0; oi < 4; ++oi) {
      float bb = b3[oc + 64 * oi];
      #pragma unroll
      for (int r = 0; r < 4; ++r)
        ys[(4 * rg + r) * 260 + oc + 64 * oi] = acc[oi][r] + bb;
    }
  }
  __syncthreads();

  // ---- iteration-invariant operand fragments (registers) ----
  short8 aah[2][4], aal[2][4];     // phase-A A-op: A[m-tile T][K-half wv]
  f4v binit[2];
  if (wv < 2) {
    #pragma unroll
    for (int T = 0; T < 2; ++T)
      #pragma unroll
      for (int s = 0; s < 4; ++s) {
        const float* ap = A + (size_t)(l15 + 16 * T) * 256 + 128 * wv + 32 * s + 8 * quad;
        float v[8];
        #pragma unroll
        for (int j = 0; j < 8; ++j) v[j] = ap[j];
        split8(v, aah[T][s], aal[T][s]);
      }
  }
  #pragma unroll
  for (int T = 0; T < 2; ++T) {
    if (wv == 0) {
      f4v bv = *(const f4v*)&bmat[(size_t)(row0 + l15) * 32 + 16 * T + 4 * quad];
      binit[T] = -bv;
    } else {
      binit[T] = f4v{0.f, 0.f, 0.f, 0.f};
    }
  }

  short8 kanh[4], kanl[4];         // phase-B A-op: KA^T n-tiles 4wv..4wv+3
  #pragma unroll
  for (int u = 0; u < 4; ++u) {
    const float* kp = KAT + (size_t)(16 * (4 * wv + u) + l15) * 32 + 8 * quad;
    float v[8];
    #pragma unroll
    for (int j = 0; j < 8; ++j) v[j] = kp[j];
    split8(v, kanh[u], kanl[u]);
  }

  // ---- zfrag write offsets (it-invariant) ----
  int zoff[4];
  #pragma unroll
  for (int u = 0; u < 4; ++u) {
    const int lanep = (2 * (u & 1) + (quad >> 1)) * 16 + l15;
    const int sp = 2 * (wv & 1) + (u >> 1);
    zoff[u] = (((wv >> 1) * 4 + sp) * 2) * 256 + lanep * 4 + 2 * (quad & 1);
  }

  // ---- init z registers from y; publish zfrag ----
  float zr[4][4];
  #pragma unroll
  for (int u = 0; u < 4; ++u) {
    f4v yv = *(const f4v*)&ys[l15 * 260 + 64 * wv + 16 * u + 4 * quad];
    #pragma unroll
    for (int r = 0; r < 4; ++r) zr[u][r] = yv[r];
    unsigned h0, l0, h1_, l1_;
    split_pair(zr[u][0], zr[u][1], h0, l0);
    split_pair(zr[u][2], zr[u][3], h1_, l1_);
    u2v hv; hv[0] = h0; hv[1] = h1_;
    u2v lv; lv[0] = l0; lv[1] = l1_;
    *(u2v*)&zfrag[zoff[u]] = hv;
    *(u2v*)&zfrag[zoff[u] + 256] = lv;
  }
  __syncthreads();

  const int niter = n_iter_p[0];

  for (int it = 0; it <= niter; ++it) {
    // ======== Phase A (waves 0,1): r^T = A z^T - b^T ========
    if (wv < 2) {
      const int kh = wv;
      short8 zfh[4], zfl[4];
      #pragma unroll
      for (int s = 0; s < 4; ++s) {
        zfh[s] = *(const short8*)&zfrag[((kh * 4 + s) * 2 + 0) * 256 + lane * 4];
        zfl[s] = *(const short8*)&zfrag[((kh * 4 + s) * 2 + 1) * 256 + lane * 4];
      }
      #pragma unroll
      for (int T = 0; T < 2; ++T) {
        f4v c0 = binit[T];
        f4v c1 = {0.f, 0.f, 0.f, 0.f};
        #pragma unroll
        for (int s = 0; s < 4; ++s) {
          f4v cc = (s & 1) ? c1 : c0;
          cc = mfma16(aah[T][s], zfh[s], cc);
          cc = mfma16(aal[T][s], zfh[s], cc);
          cc = mfma16(aah[T][s], zfl[s], cc);
          if (s & 1) c1 = cc; else c0 = cc;
        }
        f4v rA = c0 + c1;
        unsigned h0, l0, h1_, l1_;
        split_pair(rA[0], rA[1], h0, l0);
        split_pair(rA[2], rA[3], h1_, l1_);
        const int lanep = (2 * T + (quad >> 1)) * 16 + l15;
        const int rb = (kh * 2) * 256 + lanep * 4 + 2 * (quad & 1);
        u2v hv; hv[0] = h0; hv[1] = h1_;
        u2v lv; lv[0] = l0; lv[1] = l1_;
        *(u2v*)&rfrag[rb] = hv;
        *(u2v*)&rfrag[rb + 256] = lv;
      }
    }
    __syncthreads();

    // ======== Phase B (all waves): w^T = KA^T r^T ========
    const short8 rh0 = *(const short8*)&rfrag[0 * 256 + lane * 4];
    const short8 rl0 = *(const short8*)&rfrag[1 * 256 + lane * 4];
    const short8 rh1 = *(const short8*)&rfrag[2 * 256 + lane * 4];
    const short8 rl1 = *(const short8*)&rfrag[3 * 256 + lane * 4];
    f4v cB[4];
    #pragma unroll
    for (int u = 0; u < 4; ++u) {
      f4v cc = {0.f, 0.f, 0.f, 0.f};
      cc = mfma16(kanh[u], rh0, cc);
      cc = mfma16(kanl[u], rh0, cc);
      cc = mfma16(kanh[u], rl0, cc);
      cc = mfma16(kanh[u], rh1, cc);
      cc = mfma16(kanl[u], rh1, cc);
      cc = mfma16(kanh[u], rl1, cc);
      cB[u] = cc;
    }

    if (it < niter) {
      // update in registers; publish zfrag
      #pragma unroll
      for (int u = 0; u < 4; ++u) {
        #pragma unroll
        for (int r = 0; r < 4; ++r) {
          float z = zr[u][r], wvv = cB[u][r];
          float vv = fminf(fmaxf(z - 2.f * wvv, 0.f), 1.f);  // clip(2u - z)
          zr[u][r] = fmaf(1.7f, vv - z + wvv, z);            // z += 1.7*(v-u)
        }
        unsigned h0, l0, h1_, l1_;
        split_pair(zr[u][0], zr[u][1], h0, l0);
        split_pair(zr[u][2], zr[u][3], h1_, l1_);
        u2v hv; hv[0] = h0; hv[1] = h1_;
        u2v lv; lv[0] = l0; lv[1] = l1_;
        *(u2v*)&zfrag[zoff[u]] = hv;
        *(u2v*)&zfrag[zoff[u] + 256] = lv;
      }
      __syncthreads();
    } else {
      #pragma unroll
      for (int u = 0; u < 4; ++u) {
        f4v ov;
        #pragma unroll
        for (int r = 0; r < 4; ++r) ov[r] = zr[u][r] - cB[u][r];
        *(f4v*)&out[(size_t)(row0 + l15) * 256 + 64 * wv + 16 * u + 4 * quad] = ov;
      }
    }
  }
}

// ---------------------------------------------------------------------------
extern "C" void kernel_launch(void* const* d_in, const int* in_sizes, int n_in,
                              void* d_out, int out_size, void* d_ws, size_t ws_size,
                              hipStream_t stream) {
  const float* x    = (const float*)d_in[0];
  const float* bmat = (const float*)d_in[1];
  const float* W1   = (const float*)d_in[2];
  const float* b1   = (const float*)d_in[3];
  const float* W2   = (const float*)d_in[4];
  const float* b2   = (const float*)d_in[5];
  const float* W3   = (const float*)d_in[6];
  const float* b3   = (const float*)d_in[7];
  const float* A    = (const float*)d_in[8];
  const int*  n_it  = (const int*)d_in[10];
  float* KAT = (float*)d_ws;          // 256*32 floats = 32 KB
  float* out = (float*)d_out;

  hipLaunchKernelGGL(k_prep, dim3(1), dim3(256), 0, stream, A, KAT);
  hipLaunchKernelGGL(k_main, dim3(Bn / TR), dim3(256), 0, stream,
                     x, bmat, W1, b1, W2, b2, W3, b3, A, KAT, n_it, out);
}

// Round 5
// 254.525 us; speedup vs baseline: 4.1178x; 1.1554x over previous
//
#include <hip/hip_runtime.h>
#include <hip/hip_bf16.h>

typedef float    f4v    __attribute__((ext_vector_type(4)));
typedef short    short8 __attribute__((ext_vector_type(8)));
typedef unsigned u2v    __attribute__((ext_vector_type(2)));

constexpr int Bn = 4096, D_IN = 128, HID = 200, DIM = 256, TR = 16;

// ---------------------------------------------------------------------------
// k_prep: KAT[n][m] = (inv(A A^T + 1e-6 I) @ A)^T   -> d_ws (256*32 floats)
// 1024 threads: G one dot/thread; GJ 2 elems/thread; KAT 8 results/thread.
// ---------------------------------------------------------------------------
__global__ __launch_bounds__(1024) void k_prep(const float* __restrict__ A,
                                               float* __restrict__ KAT) {
  __shared__ float As[32 * 256];
  __shared__ float Gm[32 * 68];   // [32][64] augmented [G|I], stride 68
  __shared__ float ck[32];
  const int t = threadIdx.x;

  for (int i = t; i < 2048; i += 1024) ((f4v*)As)[i] = ((const f4v*)A)[i];

  // G = A A^T + eps I: thread t <-> (i,j), dot over 256 via global f4 (L2-hot)
  {
    const int gi = t >> 5, gj = t & 31;
    f4v acc = {0.f, 0.f, 0.f, 0.f};
    const f4v* ai = (const f4v*)(A + gi * 256);
    const f4v* aj = (const f4v*)(A + gj * 256);
    for (int k = 0; k < 64; ++k) acc += ai[k] * aj[k];
    float s = acc[0] + acc[1] + acc[2] + acc[3];
    if (gi == gj) s += 1e-6f;
    Gm[gi * 68 + gj] = s;
    Gm[gi * 68 + 32 + gj] = (gi == gj) ? 1.f : 0.f;
  }
  __syncthreads();

  // Gauss-Jordan (diagonally dominant; no pivoting)
  for (int k = 0; k < 32; ++k) {
    if (t < 32) ck[t] = Gm[t * 68 + k];
    __syncthreads();
    float ip = 1.f / ck[k];
    if (t < 64) Gm[k * 68 + t] *= ip;
    __syncthreads();
    for (int idx = t; idx < 2048; idx += 1024) {
      int i = idx >> 6, j = idx & 63;
      if (i != k) Gm[i * 68 + j] = fmaf(-ck[i], Gm[k * 68 + j], Gm[i * 68 + j]);
    }
    __syncthreads();
  }

  // KAT[j][m] = sum_n Ginv[m][n] * As[n][j]; thread = (j = t&255, mq = t>>8)
  {
    const int j = t & 255, mq = t >> 8;   // mq in 0..3 -> m = 8mq..8mq+7
    float colA[32];
    #pragma unroll
    for (int n = 0; n < 32; ++n) colA[n] = As[n * 256 + j];
    float res[8];
    #pragma unroll
    for (int mm = 0; mm < 8; ++mm) {
      const float* g = &Gm[(8 * mq + mm) * 68 + 32];
      float s = 0.f;
      #pragma unroll
      for (int n = 0; n < 32; ++n) s = fmaf(g[n], colA[n], s);
      res[mm] = s;
    }
    f4v v0 = {res[0], res[1], res[2], res[3]};
    f4v v1 = {res[4], res[5], res[6], res[7]};
    *(f4v*)&KAT[j * 32 + 8 * mq] = v0;
    *(f4v*)&KAT[j * 32 + 8 * mq + 4] = v1;
  }
}

// ---- split-bf16 helpers ----------------------------------------------------
__device__ inline unsigned cvt2(float x, float y) {
  union { __hip_bfloat162 h; unsigned u; } c;
  c.h = __float22bfloat162_rn(float2{x, y});
  return c.u;   // low16 = bf16(x), high16 = bf16(y)
}
__device__ inline void split_pair(float x, float y, unsigned& hp, unsigned& lp) {
  hp = cvt2(x, y);
  float hx = __uint_as_float(hp << 16);
  float hy = __uint_as_float(hp & 0xffff0000u);
  lp = cvt2(x - hx, y - hy);
}
union S8U { unsigned u[4]; short8 s; };
__device__ inline void split8(const float v[8], short8& hi, short8& lo) {
  S8U h, l;
  #pragma unroll
  for (int d = 0; d < 4; ++d) split_pair(v[2 * d], v[2 * d + 1], h.u[d], l.u[d]);
  hi = h.s; lo = l.s;
}
__device__ inline f4v mfma16(short8 a, short8 b, f4v c) {
  return __builtin_amdgcn_mfma_f32_16x16x32_bf16(a, b, c, 0, 0, 0);
}

// ---------------------------------------------------------------------------
// k_main: 512 threads (8 waves), TR=16, grid 256 -> 2 waves/SIMD.
// Phase A (waves 0-3): (T=wv&1, kh=wv>>1): partial r^T = A z^T - b^T, 12 MFMA.
// Phase B (all 8):     wave owns n-tiles U=2wv,2wv+1: w^T = KA^T r^T, 12 MFMA;
//                      z update in registers; zfrag republished in B-op order.
// ---------------------------------------------------------------------------
__global__ __launch_bounds__(512, 1) void k_main(
    const float* __restrict__ x,  const float* __restrict__ bmat,
    const float* __restrict__ W1, const float* __restrict__ b1,
    const float* __restrict__ W2, const float* __restrict__ b2,
    const float* __restrict__ W3, const float* __restrict__ b3,
    const float* __restrict__ A,  const float* __restrict__ KAT,
    const int* __restrict__ n_iter_p, float* __restrict__ out) {

  __shared__ float ubuf[8768];                     // MLP scratch; later y[16][260]
  __shared__ __align__(16) unsigned zfrag[4096];   // [kh][s][hi/lo][512B frag]
  __shared__ __align__(16) unsigned rfrag[1024];   // [kh][hi/lo][512B frag]

  const int t = threadIdx.x;
  const int lane = t & 63, wv = t >> 6, quad = lane >> 4, l15 = lane & 15;
  const int row0 = blockIdx.x * TR;

  float* xs = ubuf;            // [16][132]
  float* h1 = ubuf + 2112;     // [16][208]
  float* h2 = ubuf + 5440;     // [16][208]
  float* ys = ubuf;            // [16][260] (xs+h1 dead by then)

  if (t < 512) {
    int r = t >> 5, c4 = t & 31;
    *(f4v*)&xs[r * 132 + 4 * c4] = *(const f4v*)&x[(size_t)(row0 + r) * 128 + 4 * c4];
  }
  __syncthreads();

  // ---- MLP: 2 rows per wave, register-blocked ----
  {
    const int rg = wv, oc = lane;
    const bool g3 = (oc < 8);    // HID=200: col oc+192 valid iff oc<8
    float acc[4][2];

    // L1: 128 -> 200, relu
    #pragma unroll
    for (int oi = 0; oi < 4; ++oi) { acc[oi][0] = 0.f; acc[oi][1] = 0.f; }
    for (int k4 = 0; k4 < 32; ++k4) {
      f4v xv0 = *(const f4v*)&xs[(2 * rg + 0) * 132 + 4 * k4];
      f4v xv1 = *(const f4v*)&xs[(2 * rg + 1) * 132 + 4 * k4];
      #pragma unroll
      for (int kk = 0; kk < 4; ++kk) {
        const float* wr = W1 + (4 * k4 + kk) * 200 + oc;
        float w0 = wr[0], w1c = wr[64], w2c = wr[128];
        float w3c = g3 ? wr[192] : 0.f;
        acc[0][0] = fmaf(xv0[kk], w0, acc[0][0]);  acc[0][1] = fmaf(xv1[kk], w0, acc[0][1]);
        acc[1][0] = fmaf(xv0[kk], w1c, acc[1][0]); acc[1][1] = fmaf(xv1[kk], w1c, acc[1][1]);
        acc[2][0] = fmaf(xv0[kk], w2c, acc[2][0]); acc[2][1] = fmaf(xv1[kk], w2c, acc[2][1]);
        acc[3][0] = fmaf(xv0[kk], w3c, acc[3][0]); acc[3][1] = fmaf(xv1[kk], w3c, acc[3][1]);
      }
    }
    #pragma unroll
    for (int oi = 0; oi < 4; ++oi) {
      if (oi == 3 && !g3) continue;
      float bb = b1[oc + 64 * oi];
      h1[(2 * rg + 0) * 208 + oc + 64 * oi] = fmaxf(acc[oi][0] + bb, 0.f);
      h1[(2 * rg + 1) * 208 + oc + 64 * oi] = fmaxf(acc[oi][1] + bb, 0.f);
    }
    __syncthreads();

    // L2: 200 -> 200, relu
    #pragma unroll
    for (int oi = 0; oi < 4; ++oi) { acc[oi][0] = 0.f; acc[oi][1] = 0.f; }
    for (int k4 = 0; k4 < 50; ++k4) {
      f4v xv0 = *(const f4v*)&h1[(2 * rg + 0) * 208 + 4 * k4];
      f4v xv1 = *(const f4v*)&h1[(2 * rg + 1) * 208 + 4 * k4];
      #pragma unroll
      for (int kk = 0; kk < 4; ++kk) {
        const float* wr = W2 + (4 * k4 + kk) * 200 + oc;
        float w0 = wr[0], w1c = wr[64], w2c = wr[128];
        float w3c = g3 ? wr[192] : 0.f;
        acc[0][0] = fmaf(xv0[kk], w0, acc[0][0]);  acc[0][1] = fmaf(xv1[kk], w0, acc[0][1]);
        acc[1][0] = fmaf(xv0[kk], w1c, acc[1][0]); acc[1][1] = fmaf(xv1[kk], w1c, acc[1][1]);
        acc[2][0] = fmaf(xv0[kk], w2c, acc[2][0]); acc[2][1] = fmaf(xv1[kk], w2c, acc[2][1]);
        acc[3][0] = fmaf(xv0[kk], w3c, acc[3][0]); acc[3][1] = fmaf(xv1[kk], w3c, acc[3][1]);
      }
    }
    #pragma unroll
    for (int oi = 0; oi < 4; ++oi) {
      if (oi == 3 && !g3) continue;
      float bb = b2[oc + 64 * oi];
      h2[(2 * rg + 0) * 208 + oc + 64 * oi] = fmaxf(acc[oi][0] + bb, 0.f);
      h2[(2 * rg + 1) * 208 + oc + 64 * oi] = fmaxf(acc[oi][1] + bb, 0.f);
    }
    __syncthreads();

    // L3: 200 -> 256 (no relu) -> ys
    #pragma unroll
    for (int oi = 0; oi < 4; ++oi) { acc[oi][0] = 0.f; acc[oi][1] = 0.f; }
    for (int k4 = 0; k4 < 50; ++k4) {
      f4v xv0 = *(const f4v*)&h2[(2 * rg + 0) * 208 + 4 * k4];
      f4v xv1 = *(const f4v*)&h2[(2 * rg + 1) * 208 + 4 * k4];
      #pragma unroll
      for (int kk = 0; kk < 4; ++kk) {
        const float* wr = W3 + (4 * k4 + kk) * 256 + oc;
        float w0 = wr[0], w1c = wr[64], w2c = wr[128], w3c = wr[192];
        acc[0][0] = fmaf(xv0[kk], w0, acc[0][0]);  acc[0][1] = fmaf(xv1[kk], w0, acc[0][1]);
        acc[1][0] = fmaf(xv0[kk], w1c, acc[1][0]); acc[1][1] = fmaf(xv1[kk], w1c, acc[1][1]);
        acc[2][0] = fmaf(xv0[kk], w2c, acc[2][0]); acc[2][1] = fmaf(xv1[kk], w2c, acc[2][1]);
        acc[3][0] = fmaf(xv0[kk], w3c, acc[3][0]); acc[3][1] = fmaf(xv1[kk], w3c, acc[3][1]);
      }
    }
    __syncthreads();   // all reads of h2/xs done before ys overlays ubuf
    #pragma unroll
    for (int oi = 0; oi < 4; ++oi) {
      float bb = b3[oc + 64 * oi];
      ys[(2 * rg + 0) * 260 + oc + 64 * oi] = acc[oi][0] + bb;
      ys[(2 * rg + 1) * 260 + oc + 64 * oi] = acc[oi][1] + bb;
    }
  }
  __syncthreads();

  // ---- iteration-invariant operand fragments (registers) ----
  const int T  = wv & 1;         // phase-A m-tile
  const int kh = wv >> 1;        // phase-A K-half (valid for wv<4)

  short8 aah[4], aal[4];         // phase-A A-op: A rows 16T.., K-half kh
  f4v binit = {0.f, 0.f, 0.f, 0.f};
  if (wv < 4) {
    #pragma unroll
    for (int s = 0; s < 4; ++s) {
      const float* ap = A + (size_t)(l15 + 16 * T) * 256 + 128 * kh + 32 * s + 8 * quad;
      float v[8];
      #pragma unroll
      for (int j = 0; j < 8; ++j) v[j] = ap[j];
      split8(v, aah[s], aal[s]);
    }
    if (wv < 2) {   // kh == 0 carries the -b term
      f4v bv = *(const f4v*)&bmat[(size_t)(row0 + l15) * 32 + 16 * T + 4 * quad];
      binit = -bv;
    }
  }

  short8 kanh[2], kanl[2];       // phase-B A-op: KAT n-tiles U=2wv,2wv+1
  #pragma unroll
  for (int u = 0; u < 2; ++u) {
    const int U = 2 * wv + u;
    const float* kp = KAT + (size_t)(16 * U + l15) * 32 + 8 * quad;
    float v[8];
    #pragma unroll
    for (int j = 0; j < 8; ++j) v[j] = kp[j];
    split8(v, kanh[u], kanl[u]);
  }

  // ---- zfrag write offsets: n = 16U + 4quad + r; block (kh=U>>3, s=(U>>1)&3);
  //      short pos = 128*(2(U&1)+(quad>>1)) + 8*l15 + 4*(quad&1) + r
  int zoff[2];
  #pragma unroll
  for (int u = 0; u < 2; ++u) {
    const int U = 2 * wv + u;
    const int qp = 2 * (U & 1) + (quad >> 1);
    zoff[u] = (((U >> 3) * 4 + ((U >> 1) & 3)) * 2) * 256
              + qp * 64 + l15 * 4 + 2 * (quad & 1);
  }

  // ---- init z registers from y; publish zfrag ----
  float zr[2][4];
  #pragma unroll
  for (int u = 0; u < 2; ++u) {
    const int U = 2 * wv + u;
    f4v yv = *(const f4v*)&ys[l15 * 260 + 16 * U + 4 * quad];
    #pragma unroll
    for (int r = 0; r < 4; ++r) zr[u][r] = yv[r];
    unsigned h0, l0, h1_, l1_;
    split_pair(zr[u][0], zr[u][1], h0, l0);
    split_pair(zr[u][2], zr[u][3], h1_, l1_);
    u2v hv; hv[0] = h0; hv[1] = h1_;
    u2v lv; lv[0] = l0; lv[1] = l1_;
    *(u2v*)&zfrag[zoff[u]] = hv;
    *(u2v*)&zfrag[zoff[u] + 256] = lv;
  }
  __syncthreads();

  const int niter = n_iter_p[0];

  for (int it = 0; it <= niter; ++it) {
    // ======== Phase A (waves 0-3): partial r^T = A z^T - b^T ========
    if (wv < 4) {
      short8 zfh[4], zfl[4];
      #pragma unroll
      for (int s = 0; s < 4; ++s) {
        zfh[s] = *(const short8*)&zfrag[((kh * 4 + s) * 2 + 0) * 256 + lane * 4];
        zfl[s] = *(const short8*)&zfrag[((kh * 4 + s) * 2 + 1) * 256 + lane * 4];
      }
      f4v c0 = binit, c1 = {0.f, 0.f, 0.f, 0.f};
      #pragma unroll
      for (int s = 0; s < 4; ++s) {
        f4v cc = (s & 1) ? c1 : c0;
        cc = mfma16(aah[s], zfh[s], cc);
        cc = mfma16(aal[s], zfh[s], cc);
        cc = mfma16(aah[s], zfl[s], cc);
        if (s & 1) c1 = cc; else c0 = cc;
      }
      f4v rA = c0 + c1;
      unsigned h0, l0, h1_, l1_;
      split_pair(rA[0], rA[1], h0, l0);
      split_pair(rA[2], rA[3], h1_, l1_);
      const int lanep = (2 * T + (quad >> 1)) * 16 + l15;
      const int rb = kh * 512 + lanep * 4 + 2 * (quad & 1);
      u2v hv; hv[0] = h0; hv[1] = h1_;
      u2v lv; lv[0] = l0; lv[1] = l1_;
      *(u2v*)&rfrag[rb] = hv;
      *(u2v*)&rfrag[rb + 256] = lv;
    }
    __syncthreads();

    // ======== Phase B (all waves): w^T = KA^T r^T for U = 2wv, 2wv+1 ========
    const short8 rh0 = *(const short8*)&rfrag[0 * 256 + lane * 4];
    const short8 rl0 = *(const short8*)&rfrag[1 * 256 + lane * 4];
    const short8 rh1 = *(const short8*)&rfrag[2 * 256 + lane * 4];
    const short8 rl1 = *(const short8*)&rfrag[3 * 256 + lane * 4];
    f4v cB[2];
    #pragma unroll
    for (int u = 0; u < 2; ++u) {
      f4v cc = {0.f, 0.f, 0.f, 0.f};
      cc = mfma16(kanh[u], rh0, cc);
      cc = mfma16(kanl[u], rh0, cc);
      cc = mfma16(kanh[u], rl0, cc);
      cc = mfma16(kanh[u], rh1, cc);
      cc = mfma16(kanl[u], rh1, cc);
      cc = mfma16(kanh[u], rl1, cc);
      cB[u] = cc;
    }

    if (it < niter) {
      #pragma unroll
      for (int u = 0; u < 2; ++u) {
        #pragma unroll
        for (int r = 0; r < 4; ++r) {
          float z = zr[u][r], wvv = cB[u][r];
          float vv = fminf(fmaxf(z - 2.f * wvv, 0.f), 1.f);  // clip(2u - z)
          zr[u][r] = fmaf(1.7f, vv - z + wvv, z);            // z += 1.7*(v-u)
        }
        unsigned h0, l0, h1_, l1_;
        split_pair(zr[u][0], zr[u][1], h0, l0);
        split_pair(zr[u][2], zr[u][3], h1_, l1_);
        u2v hv; hv[0] = h0; hv[1] = h1_;
        u2v lv; lv[0] = l0; lv[1] = l1_;
        *(u2v*)&zfrag[zoff[u]] = hv;
        *(u2v*)&zfrag[zoff[u] + 256] = lv;
      }
      __syncthreads();
    } else {
      #pragma unroll
      for (int u = 0; u < 2; ++u) {
        const int U = 2 * wv + u;
        f4v ov;
        #pragma unroll
        for (int r = 0; r < 4; ++r) ov[r] = zr[u][r] - cB[u][r];
        *(f4v*)&out[(size_t)(row0 + l15) * 256 + 16 * U + 4 * quad] = ov;
      }
    }
  }
}

// ---------------------------------------------------------------------------
extern "C" void kernel_launch(void* const* d_in, const int* in_sizes, int n_in,
                              void* d_out, int out_size, void* d_ws, size_t ws_size,
                              hipStream_t stream) {
  const float* x    = (const float*)d_in[0];
  const float* bmat = (const float*)d_in[1];
  const float* W1   = (const float*)d_in[2];
  const float* b1   = (const float*)d_in[3];
  const float* W2   = (const float*)d_in[4];
  const float* b2   = (const float*)d_in[5];
  const float* W3   = (const float*)d_in[6];
  const float* b3   = (const float*)d_in[7];
  const float* A    = (const float*)d_in[8];
  const int*  n_it  = (const int*)d_in[10];
  float* KAT = (float*)d_ws;          // 256*32 floats = 32 KB
  float* out = (float*)d_out;

  hipLaunchKernelGGL(k_prep, dim3(1), dim3(1024), 0, stream, A, KAT);
  hipLaunchKernelGGL(k_main, dim3(Bn / TR), dim3(512), 0, stream,
                     x, bmat, W1, b1, W2, b2, W3, b3, A, KAT, n_it, out);
}